// Round 7
// baseline (2095.677 us; speedup 1.0000x reference)
//
#include <hip/hip_runtime.h>

#define SEQ 512
#define TOT 514                 // 512 scan steps + 2 autoregressive steps
#define BH  65536               // 64 rows * 1024 hidden = elems per h/x timestep
#define NBUF (TOT + 1)          // h buffers: h[0]=hx0, h[t+1] = output of step t

typedef _Float16 f16x8 __attribute__((ext_vector_type(8)));
typedef float f32x4 __attribute__((ext_vector_type(4)));

__device__ __forceinline__ unsigned short f2h_bits(float f) {
  union { _Float16 h; unsigned short s; } u; u.h = (_Float16)f; return u.s;
}

__device__ __forceinline__ float fast_sigmoid(float x) {
  return 1.f / (1.f + __expf(-x));
}
__device__ __forceinline__ float fast_tanh(float x) {
  float e = __expf(-2.f * fabsf(x));
  float r = (1.f - e) / (1.f + e);
  return copysignf(r, x);
}

// SWAR: nonzero iff any 16-bit halfword of u equals 0xFFFF (the sentinel).
// |h|<1 strictly, so published f16 values can never be 0xFFFF (-NaN).
__device__ __forceinline__ unsigned long long dirty16(unsigned long long u) {
  unsigned long long n = ~u;   // sentinel halfword -> 0x0000
  return (n - 0x0001000100010001ULL) & ~n & 0x8000800080008000ULL;
}

// Convert x [512,64,1024] fp32 -> f16 (row-major) and hx0 -> blocked H layout
// H[t][q][s][r:16][u:16] (each producer block's slice = 512B contiguous).
__global__ void cvt_kernel(const float* __restrict__ x, const float* __restrict__ hx0,
                           unsigned short* __restrict__ X16, unsigned short* __restrict__ H0) {
  const long long n4x = (long long)SEQ * BH / 4;
  const long long n4h = BH / 4;
  const long long stride = (long long)gridDim.x * blockDim.x;
  for (long long i = (long long)blockIdx.x * blockDim.x + threadIdx.x;
       i < n4x + n4h; i += stride) {
    const float* src; unsigned short* dst;
    if (i < n4x) {
      src = x + 4 * i; dst = X16 + 4 * i;
    } else {
      long long e = (i - n4x) * 4;         // blocked linear offset
      int u0 = e & 15, r = (e >> 4) & 15, sl = (e >> 8) & 63, qq = (int)(e >> 14);
      src = hx0 + (qq * 16 + r) * 1024 + sl * 16 + u0;
      dst = H0 + e;
    }
    float4 v = *(const float4*)src;
    union { unsigned short s[4]; unsigned long long u; } pk;
    pk.s[0] = f2h_bits(v.x); pk.s[1] = f2h_bits(v.y);
    pk.s[2] = f2h_bits(v.z); pk.s[3] = f2h_bits(v.w);
    *(unsigned long long*)dst = pk.u;
  }
}

// Persistent LSTM kernel. Grid = 256 blocks (1/CU), 256 threads (4 waves).
// block -> (batch quarter q: rows [16q,16q+16), unit slice ub = s*16).
// Wave w owns K-slice [w*256,+256) of BOTH W_ih and W_hh, register-resident.
// Sync design: NO flags. H16 is pre-filled with 0xFF; producers publish h;
// consumers poll the data words until no 0xFFFF halfword remains.
//
// Round-7 change vs 1737us: CHUNK-WISE MFMA-ON-ARRIVAL. The h-MFMA for
// k-iter i needs only chunk i, not all 8. Per sweep: issue re-polls for
// still-dirty chunks, then run the MFMAs of newly-clean chunks INSIDE the
// re-poll's vmcnt shadow. This (a) shrinks the post-discovery serial tail
// from 32 MFMAs (~620cyc) to the last chunk's 4 (~80cyc), and (b) overlaps
// sweep latency with useful work (halves discovery quantization).
// Publish stays atomic-swap (r6: marginally best). All control flow is
// wave-uniform (per-chunk __any votes).
__global__ __launch_bounds__(256, 1)
void lstm_kernel(const float* __restrict__ cx0,
                 const float* __restrict__ W_ih, const float* __restrict__ W_hh,
                 const float* __restrict__ b_ih, const float* __restrict__ b_hh,
                 const unsigned short* __restrict__ X16,
                 unsigned short* __restrict__ H16,
                 float* __restrict__ out) {
  __shared__ float red[2][4][16][80];       // [parity][wave][m][n]

  const int tid  = threadIdx.x;
  const int wave = tid >> 6;
  const int lane = tid & 63;
  const int u16v = lane & 15;               // MFMA m (A row) / n (B col) index
  const int q4   = lane >> 4;               // MFMA quad
  // XCD-clustered mapping: blocks round-robin XCDs by blockIdx.x & 7, so
  // quarter q = pair of XCDs {2q, 2q+1}; s bijective within the quarter.
  const int q    = (blockIdx.x & 7) >> 1;                       // batch quarter
  const int s    = (blockIdx.x >> 3) | ((blockIdx.x & 1) << 5); // unit-slice
  const int ub   = s * 16;                  // hidden-unit base
  const int kb   = wave * 256;              // this wave's K-slice (both matrices)

  // ---------- stage weight B-fragments into registers (fp32 -> f16) ----------
  // B layout for mfma_f32_16x16x32_f16: B[k = q4*8+j][n = lane&15]; row-major
  // W[col][k] matches k-contiguity exactly.
  f16x8 bfx[4][8], bfh[4][8];
#pragma unroll
  for (int g = 0; g < 4; ++g) {
    const float* wi = W_ih + (size_t)((g << 10) + ub + u16v) * 1024 + kb + q4 * 8;
    const float* wh = W_hh + (size_t)((g << 10) + ub + u16v) * 1024 + kb + q4 * 8;
#pragma unroll
    for (int i = 0; i < 8; ++i) {
      float4 x0 = *(const float4*)(wi + i * 32);
      float4 x1 = *(const float4*)(wi + i * 32 + 4);
      float4 h0 = *(const float4*)(wh + i * 32);
      float4 h1 = *(const float4*)(wh + i * 32 + 4);
      f16x8 bx, bh;
      bx[0] = (_Float16)x0.x; bx[1] = (_Float16)x0.y; bx[2] = (_Float16)x0.z; bx[3] = (_Float16)x0.w;
      bx[4] = (_Float16)x1.x; bx[5] = (_Float16)x1.y; bx[6] = (_Float16)x1.z; bx[7] = (_Float16)x1.w;
      bh[0] = (_Float16)h0.x; bh[1] = (_Float16)h0.y; bh[2] = (_Float16)h0.z; bh[3] = (_Float16)h0.w;
      bh[4] = (_Float16)h1.x; bh[5] = (_Float16)h1.y; bh[6] = (_Float16)h1.z; bh[7] = (_Float16)h1.w;
      bfx[g][i] = bx; bfh[g][i] = bh;
    }
  }

  // ---------- per-thread recurrent state (elementwise mapping) ----------
  const int er = tid >> 4, eu = tid & 15;   // (row-in-quarter, unit-in-slice)
  const int rge = q * 16 + er;              // global batch row
  float c = cx0[rge * 1024 + ub + eu];
  const float bi  = b_ih[       ub + eu] + b_hh[       ub + eu];
  const float bfg = b_ih[1024 + ub + eu] + b_hh[1024 + ub + eu];
  const float bg  = b_ih[2048 + ub + eu] + b_hh[2048 + ub + eu];
  const float bo  = b_ih[3072 + ub + eu] + b_hh[3072 + ub + eu];

  // x A-fragment base (row-major [64,1024] f16): A[m=lane&15][k=q4*8+j]
  const size_t xbase = (size_t)(q * 16 + u16v) * 1024 + kb + q4 * 8;
  // h A-fragment base (blocked layout): element offset within a timestep
  const size_t hfrag = ((size_t)(q * 64 + wave * 16 + (q4 >> 1)) << 8)
                       + u16v * 16 + (q4 & 1) * 8;     // + i*512 per k-iter
  // this block's publish offset within a timestep (contiguous per block)
  const size_t puboff = ((size_t)(q * 64 + s) << 8) + tid;

  for (int t = 0; t < TOT; ++t) {
    f32x4 a0 = {0.f, 0.f, 0.f, 0.f}, a1 = a0, a2 = a0, a3 = a0;
    const bool xphase = (t < SEQ);
    const bool ar = (t >= SEQ);

    // ===== load x A-fragments first (oldest in vmcnt queue) =====
    f16x8 xf[8];
    if (xphase) {
      const unsigned short* xs = X16 + (size_t)t * BH + xbase;
#pragma unroll
      for (int i = 0; i < 8; ++i) xf[i] = *(const f16x8*)(xs + i * 32);
    }

    // ===== issue FIRST h-poll attempt before the x-MFMAs =====
    // x-MFMAs only need xf (older in queue), so the compiler can wait with
    // a partial vmcnt and the cv round-trip hides under the MFMA block.
    const unsigned short* hs = H16 + (size_t)t * BH + hfrag;
    union { unsigned long long u[2]; f16x8 v; } cv[8];
#pragma unroll
    for (int i = 0; i < 8; ++i) {
      const unsigned short* p = hs + i * 512;
      cv[i].u[0] = __hip_atomic_load((const unsigned long long*)p,
                                     __ATOMIC_RELAXED, __HIP_MEMORY_SCOPE_AGENT);
      cv[i].u[1] = __hip_atomic_load((const unsigned long long*)(p + 4),
                                     __ATOMIC_RELAXED, __HIP_MEMORY_SCOPE_AGENT);
    }
    __builtin_amdgcn_sched_barrier(0);   // keep cv issue ahead of the MFMAs

    // ===== x-phase: no dependency on h[t]; overlaps first poll transit =====
    if (xphase) {
#pragma unroll
      for (int i = 0; i < 8; ++i) {
        a0 = __builtin_amdgcn_mfma_f32_16x16x32_f16(xf[i], bfx[0][i], a0, 0, 0, 0);
        a1 = __builtin_amdgcn_mfma_f32_16x16x32_f16(xf[i], bfx[1][i], a1, 0, 0, 0);
        a2 = __builtin_amdgcn_mfma_f32_16x16x32_f16(xf[i], bfx[2][i], a2, 0, 0, 0);
        a3 = __builtin_amdgcn_mfma_f32_16x16x32_f16(xf[i], bfx[3][i], a3, 0, 0, 0);
      }
    }

    // ===== poll + consume: chunk-wise MFMA-on-arrival =====
    // Per iteration: (1) issue re-polls for still-dirty chunks (batched),
    // (2) run MFMAs of newly-clean chunks inside the re-poll vmcnt shadow,
    // (3) merge re-poll results. All votes wave-uniform.
    unsigned long long d[8];
    int rl[8];
#pragma unroll
    for (int i = 0; i < 8; ++i) {
      d[i] = dirty16(cv[i].u[0]) | dirty16(cv[i].u[1]);
      rl[i] = __any(d[i] != 0);
    }
    unsigned int pend = 0xFFu;             // chunks not yet MFMA-consumed
    while (true) {
      // (1) issue phase
      unsigned long long nv0[8], nv1[8];
#pragma unroll
      for (int i = 0; i < 8; ++i) {
        if (rl[i]) {
          const unsigned short* p = hs + i * 512;
          nv0[i] = __hip_atomic_load((const unsigned long long*)p,
                                     __ATOMIC_RELAXED, __HIP_MEMORY_SCOPE_AGENT);
          nv1[i] = __hip_atomic_load((const unsigned long long*)(p + 4),
                                     __ATOMIC_RELAXED, __HIP_MEMORY_SCOPE_AGENT);
        }
      }
      __builtin_amdgcn_sched_barrier(0);   // pin: issues before MFMAs/uses

      // (2) consume phase: MFMAs execute while re-polls are in flight
#pragma unroll
      for (int i = 0; i < 8; ++i) {
        if (((pend >> i) & 1u) && !rl[i]) {
          f16x8 hf = cv[i].v;
          a0 = __builtin_amdgcn_mfma_f32_16x16x32_f16(hf, bfh[0][i], a0, 0, 0, 0);
          a1 = __builtin_amdgcn_mfma_f32_16x16x32_f16(hf, bfh[1][i], a1, 0, 0, 0);
          a2 = __builtin_amdgcn_mfma_f32_16x16x32_f16(hf, bfh[2][i], a2, 0, 0, 0);
          a3 = __builtin_amdgcn_mfma_f32_16x16x32_f16(hf, bfh[3][i], a3, 0, 0, 0);
          if (ar) {  // autoregressive: x_t := h[t], add the W_ih side too
            a0 = __builtin_amdgcn_mfma_f32_16x16x32_f16(hf, bfx[0][i], a0, 0, 0, 0);
            a1 = __builtin_amdgcn_mfma_f32_16x16x32_f16(hf, bfx[1][i], a1, 0, 0, 0);
            a2 = __builtin_amdgcn_mfma_f32_16x16x32_f16(hf, bfx[2][i], a2, 0, 0, 0);
            a3 = __builtin_amdgcn_mfma_f32_16x16x32_f16(hf, bfx[3][i], a3, 0, 0, 0);
          }
          pend &= ~(1u << i);
        }
      }
      if (pend == 0) break;

      // (3) merge phase: single wait + SWAR recompute + re-vote
#pragma unroll
      for (int i = 0; i < 8; ++i) {
        if (rl[i]) {
          cv[i].u[0] = nv0[i]; cv[i].u[1] = nv1[i];
          d[i] = dirty16(nv0[i]) | dirty16(nv1[i]);
          rl[i] = __any(d[i] != 0);
        }
      }
    }

    // C/D layout: col = lane&15, row = q4*4 + reg. Stage partials (parity buf).
    const int par = t & 1;
#pragma unroll
    for (int r = 0; r < 4; ++r) {
      red[par][wave][q4 * 4 + r][     u16v] = a0[r];
      red[par][wave][q4 * 4 + r][16 + u16v] = a1[r];
      red[par][wave][q4 * 4 + r][32 + u16v] = a2[r];
      red[par][wave][q4 * 4 + r][48 + u16v] = a3[r];
    }
    __syncthreads();   // the ONLY barrier per step (parity buffer removes WAR)

    // Reduce 4 K-partials + bias, then LSTM cell math in fp32.
    float gi = bi, gf = bfg, gg = bg, go = bo;
#pragma unroll
    for (int w2 = 0; w2 < 4; ++w2) {
      gi += red[par][w2][er][     eu];
      gf += red[par][w2][er][16 + eu];
      gg += red[par][w2][er][32 + eu];
      go += red[par][w2][er][48 + eu];
    }
    c = fast_sigmoid(gf) * c + fast_sigmoid(gi) * fast_tanh(gg);
    float h = fast_sigmoid(go) * fast_tanh(c);

    // Publish h[t+1]: pack 4 lanes' halfwords into one 8B ATOMIC SWAP
    // (executes at the LLC; fire-and-forget). The data IS the flag:
    // consumers detect non-sentinel halfwords at 8B granularity.
    {
      unsigned int v = f2h_bits(h);
      unsigned int partner = (unsigned int)__shfl_xor((int)v, 1);
      unsigned int pair = (v & 0xFFFFu) | (partner << 16);      // even lanes
      unsigned int pair2 = (unsigned int)__shfl_xor((int)pair, 2);
      unsigned long long p8 = ((unsigned long long)pair2 << 32) | pair; // lane%4==0
      if ((tid & 3) == 0)
        (void)__hip_atomic_exchange(
            (unsigned long long*)(H16 + (size_t)(t + 1) * BH + puboff),
            p8, __ATOMIC_RELAXED, __HIP_MEMORY_SCOPE_AGENT);
    }
    if (t >= SEQ) out[(size_t)(t - SEQ) * BH + rge * 1024 + ub + eu] = h;
  }
}

extern "C" void kernel_launch(void* const* d_in, const int* in_sizes, int n_in,
                              void* d_out, int out_size, void* d_ws, size_t ws_size,
                              hipStream_t stream) {
  const float* x    = (const float*)d_in[0];
  const float* hx0  = (const float*)d_in[1];
  const float* cx0  = (const float*)d_in[2];
  const float* W_ih = (const float*)d_in[3];
  const float* W_hh = (const float*)d_in[4];
  const float* b_ih = (const float*)d_in[5];
  const float* b_hh = (const float*)d_in[6];

  // Workspace: X16 (67.1 MB) | H16 (67.5 MB)  ~= 135 MB
  unsigned short* X16 = (unsigned short*)d_ws;
  unsigned short* H16 = X16 + (size_t)SEQ * BH;

  // Sentinel-fill H16 (0xFFFF halfwords), then cvt overwrites H[0] with hx0.
  hipMemsetAsync(H16, 0xFF, (size_t)NBUF * BH * sizeof(unsigned short), stream);
  cvt_kernel<<<1024, 256, 0, stream>>>(x, hx0, X16, H16);
  lstm_kernel<<<256, 256, 0, stream>>>(cx0, W_ih, W_hh, b_ih, b_hh,
                                       X16, H16, (float*)d_out);
}

// Round 8
// 2023.717 us; speedup vs baseline: 1.0356x; 1.0356x over previous
//
#include <hip/hip_runtime.h>

#define SEQ 512
#define TOT 514                 // 512 scan steps + 2 autoregressive steps
#define BH  65536               // 64 rows * 1024 hidden = elems per h/x timestep
#define NBUF (TOT + 1)          // h buffers: h[0]=hx0, h[t+1] = output of step t

typedef _Float16 f16x8 __attribute__((ext_vector_type(8)));
typedef float f32x4 __attribute__((ext_vector_type(4)));

__device__ __forceinline__ unsigned short f2h_bits(float f) {
  union { _Float16 h; unsigned short s; } u; u.h = (_Float16)f; return u.s;
}

__device__ __forceinline__ float fast_sigmoid(float x) {
  return 1.f / (1.f + __expf(-x));
}
__device__ __forceinline__ float fast_tanh(float x) {
  float e = __expf(-2.f * fabsf(x));
  float r = (1.f - e) / (1.f + e);
  return copysignf(r, x);
}

// SWAR: nonzero iff any 16-bit halfword of u equals 0xFFFF (the sentinel).
// |h|<1 strictly, so published f16 values can never be 0xFFFF (-NaN).
__device__ __forceinline__ unsigned long long dirty16(unsigned long long u) {
  unsigned long long n = ~u;   // sentinel halfword -> 0x0000
  return (n - 0x0001000100010001ULL) & ~n & 0x8000800080008000ULL;
}

// Convert x [512,64,1024] fp32 -> f16 (row-major) and hx0 -> blocked H layout
// H[t][q][s][r:16][u:16] (each producer block's slice = 512B contiguous).
__global__ void cvt_kernel(const float* __restrict__ x, const float* __restrict__ hx0,
                           unsigned short* __restrict__ X16, unsigned short* __restrict__ H0) {
  const long long n4x = (long long)SEQ * BH / 4;
  const long long n4h = BH / 4;
  const long long stride = (long long)gridDim.x * blockDim.x;
  for (long long i = (long long)blockIdx.x * blockDim.x + threadIdx.x;
       i < n4x + n4h; i += stride) {
    const float* src; unsigned short* dst;
    if (i < n4x) {
      src = x + 4 * i; dst = X16 + 4 * i;
    } else {
      long long e = (i - n4x) * 4;         // blocked linear offset
      int u0 = e & 15, r = (e >> 4) & 15, sl = (e >> 8) & 63, qq = (int)(e >> 14);
      src = hx0 + (qq * 16 + r) * 1024 + sl * 16 + u0;
      dst = H0 + e;
    }
    float4 v = *(const float4*)src;
    union { unsigned short s[4]; unsigned long long u; } pk;
    pk.s[0] = f2h_bits(v.x); pk.s[1] = f2h_bits(v.y);
    pk.s[2] = f2h_bits(v.z); pk.s[3] = f2h_bits(v.w);
    *(unsigned long long*)dst = pk.u;
  }
}

// Persistent LSTM kernel. Grid = 256 blocks (1/CU), 256 threads (4 waves).
// block -> (batch quarter q: rows [16q,16q+16), unit slice ub = s*16).
// Wave w owns K-slice [w*256,+256) of BOTH W_ih and W_hh, register-resident.
// Sync design: NO flags. H16 is pre-filled with 0xFF; producers publish h;
// consumers poll the data words until no 0xFFFF halfword remains.
//
// Round-8 change vs 1737us (r6 base; r7's MFMA-on-arrival reverted, -230us):
// PING-PONG PIPELINED POLL SWEEPS. Old sweep was serial: issue 16 loads ->
// vmcnt(0) wait (~700cyc) -> SWAR merge (~220cyc) -> reissue; discovery
// quantization = full ~1200cyc sweep. Now two unconditional buffers A/B
// alternate: while one's RT is in flight the other is merged, so checks
// happen every ~max(merge, RT/2) ~= 500-700cyc and the clean buffer's data
// is already in registers. Selective-reload logic deleted (overhead; poll
// traffic proven free in r4). Static control flow only (no runtime-indexed
// reg arrays). Publish stays 8B atomic-swap (r6).
__global__ __launch_bounds__(256, 1)
void lstm_kernel(const float* __restrict__ cx0,
                 const float* __restrict__ W_ih, const float* __restrict__ W_hh,
                 const float* __restrict__ b_ih, const float* __restrict__ b_hh,
                 const unsigned short* __restrict__ X16,
                 unsigned short* __restrict__ H16,
                 float* __restrict__ out) {
  __shared__ float red[2][4][16][80];       // [parity][wave][m][n]

  const int tid  = threadIdx.x;
  const int wave = tid >> 6;
  const int lane = tid & 63;
  const int u16v = lane & 15;               // MFMA m (A row) / n (B col) index
  const int q4   = lane >> 4;               // MFMA quad
  // XCD-clustered mapping: blocks round-robin XCDs by blockIdx.x & 7, so
  // quarter q = pair of XCDs {2q, 2q+1}; s bijective within the quarter.
  const int q    = (blockIdx.x & 7) >> 1;                       // batch quarter
  const int s    = (blockIdx.x >> 3) | ((blockIdx.x & 1) << 5); // unit-slice
  const int ub   = s * 16;                  // hidden-unit base
  const int kb   = wave * 256;              // this wave's K-slice (both matrices)

  // ---------- stage weight B-fragments into registers (fp32 -> f16) ----------
  // B layout for mfma_f32_16x16x32_f16: B[k = q4*8+j][n = lane&15]; row-major
  // W[col][k] matches k-contiguity exactly.
  f16x8 bfx[4][8], bfh[4][8];
#pragma unroll
  for (int g = 0; g < 4; ++g) {
    const float* wi = W_ih + (size_t)((g << 10) + ub + u16v) * 1024 + kb + q4 * 8;
    const float* wh = W_hh + (size_t)((g << 10) + ub + u16v) * 1024 + kb + q4 * 8;
#pragma unroll
    for (int i = 0; i < 8; ++i) {
      float4 x0 = *(const float4*)(wi + i * 32);
      float4 x1 = *(const float4*)(wi + i * 32 + 4);
      float4 h0 = *(const float4*)(wh + i * 32);
      float4 h1 = *(const float4*)(wh + i * 32 + 4);
      f16x8 bx, bh;
      bx[0] = (_Float16)x0.x; bx[1] = (_Float16)x0.y; bx[2] = (_Float16)x0.z; bx[3] = (_Float16)x0.w;
      bx[4] = (_Float16)x1.x; bx[5] = (_Float16)x1.y; bx[6] = (_Float16)x1.z; bx[7] = (_Float16)x1.w;
      bh[0] = (_Float16)h0.x; bh[1] = (_Float16)h0.y; bh[2] = (_Float16)h0.z; bh[3] = (_Float16)h0.w;
      bh[4] = (_Float16)h1.x; bh[5] = (_Float16)h1.y; bh[6] = (_Float16)h1.z; bh[7] = (_Float16)h1.w;
      bfx[g][i] = bx; bfh[g][i] = bh;
    }
  }

  // ---------- per-thread recurrent state (elementwise mapping) ----------
  const int er = tid >> 4, eu = tid & 15;   // (row-in-quarter, unit-in-slice)
  const int rge = q * 16 + er;              // global batch row
  float c = cx0[rge * 1024 + ub + eu];
  const float bi  = b_ih[       ub + eu] + b_hh[       ub + eu];
  const float bfg = b_ih[1024 + ub + eu] + b_hh[1024 + ub + eu];
  const float bg  = b_ih[2048 + ub + eu] + b_hh[2048 + ub + eu];
  const float bo  = b_ih[3072 + ub + eu] + b_hh[3072 + ub + eu];

  // x A-fragment base (row-major [64,1024] f16): A[m=lane&15][k=q4*8+j]
  const size_t xbase = (size_t)(q * 16 + u16v) * 1024 + kb + q4 * 8;
  // h A-fragment base (blocked layout): element offset within a timestep
  const size_t hfrag = ((size_t)(q * 64 + wave * 16 + (q4 >> 1)) << 8)
                       + u16v * 16 + (q4 & 1) * 8;     // + i*512 per k-iter
  // this block's publish offset within a timestep (contiguous per block)
  const size_t puboff = ((size_t)(q * 64 + s) << 8) + tid;

  union CV { unsigned long long u[2]; f16x8 v; };

#define ISSUE_POLL(buf)                                                        \
  _Pragma("unroll")                                                            \
  for (int i = 0; i < 8; ++i) {                                                \
    const unsigned short* p = hs + i * 512;                                    \
    buf[i].u[0] = __hip_atomic_load((const unsigned long long*)p,              \
                                    __ATOMIC_RELAXED, __HIP_MEMORY_SCOPE_AGENT); \
    buf[i].u[1] = __hip_atomic_load((const unsigned long long*)(p + 4),        \
                                    __ATOMIC_RELAXED, __HIP_MEMORY_SCOPE_AGENT); \
  }

#define CLEAN_CHECK(buf, ok)                                                   \
  {                                                                            \
    unsigned long long agg = 0;                                                \
    _Pragma("unroll")                                                          \
    for (int i = 0; i < 8; ++i)                                                \
      agg |= dirty16(buf[i].u[0]) | dirty16(buf[i].u[1]);                      \
    ok = __all(agg == 0);                                                      \
  }

  for (int t = 0; t < TOT; ++t) {
    f32x4 a0 = {0.f, 0.f, 0.f, 0.f}, a1 = a0, a2 = a0, a3 = a0;
    const bool xphase = (t < SEQ);

    // ===== load x A-fragments first (oldest in vmcnt queue) =====
    f16x8 xf[8];
    if (xphase) {
      const unsigned short* xs = X16 + (size_t)t * BH + xbase;
#pragma unroll
      for (int i = 0; i < 8; ++i) xf[i] = *(const f16x8*)(xs + i * 32);
    }

    // ===== issue poll sweep A before the x-MFMAs =====
    // x-MFMAs only need xf (older in queue), so the compiler waits with a
    // partial vmcnt and sweep A's round-trip hides under the MFMA block.
    const unsigned short* hs = H16 + (size_t)t * BH + hfrag;
    CV A[8], B[8];
    ISSUE_POLL(A);
    __builtin_amdgcn_sched_barrier(0);   // keep A issue ahead of the MFMAs

    // ===== x-phase: no dependency on h[t]; overlaps sweep A transit =====
    if (xphase) {
#pragma unroll
      for (int i = 0; i < 8; ++i) {
        a0 = __builtin_amdgcn_mfma_f32_16x16x32_f16(xf[i], bfx[0][i], a0, 0, 0, 0);
        a1 = __builtin_amdgcn_mfma_f32_16x16x32_f16(xf[i], bfx[1][i], a1, 0, 0, 0);
        a2 = __builtin_amdgcn_mfma_f32_16x16x32_f16(xf[i], bfx[2][i], a2, 0, 0, 0);
        a3 = __builtin_amdgcn_mfma_f32_16x16x32_f16(xf[i], bfx[3][i], a3, 0, 0, 0);
      }
    }

    // ===== issue sweep B, then alternate: check one while the other flies ===
    ISSUE_POLL(B);
    __builtin_amdgcn_sched_barrier(0);

    bool useA;
    while (true) {
      bool ok;
      // check A (B's 16 loads are younger -> wait is vmcnt(16), overlaps B)
      CLEAN_CHECK(A, ok);
      if (ok) { useA = true; break; }
      ISSUE_POLL(A);
      __builtin_amdgcn_sched_barrier(0);
      // check B (A's fresh 16 loads in flight)
      CLEAN_CHECK(B, ok);
      if (ok) { useA = false; break; }
      ISSUE_POLL(B);
      __builtin_amdgcn_sched_barrier(0);
    }

    f16x8 hf[8];
    if (useA) {
#pragma unroll
      for (int i = 0; i < 8; ++i) hf[i] = A[i].v;
    } else {
#pragma unroll
      for (int i = 0; i < 8; ++i) hf[i] = B[i].v;
    }
#pragma unroll
    for (int i = 0; i < 8; ++i) {
      a0 = __builtin_amdgcn_mfma_f32_16x16x32_f16(hf[i], bfh[0][i], a0, 0, 0, 0);
      a1 = __builtin_amdgcn_mfma_f32_16x16x32_f16(hf[i], bfh[1][i], a1, 0, 0, 0);
      a2 = __builtin_amdgcn_mfma_f32_16x16x32_f16(hf[i], bfh[2][i], a2, 0, 0, 0);
      a3 = __builtin_amdgcn_mfma_f32_16x16x32_f16(hf[i], bfh[3][i], a3, 0, 0, 0);
    }
    if (t >= SEQ) {  // autoregressive: x_t := h[t], add the W_ih side too
#pragma unroll
      for (int i = 0; i < 8; ++i) {
        a0 = __builtin_amdgcn_mfma_f32_16x16x32_f16(hf[i], bfx[0][i], a0, 0, 0, 0);
        a1 = __builtin_amdgcn_mfma_f32_16x16x32_f16(hf[i], bfx[1][i], a1, 0, 0, 0);
        a2 = __builtin_amdgcn_mfma_f32_16x16x32_f16(hf[i], bfx[2][i], a2, 0, 0, 0);
        a3 = __builtin_amdgcn_mfma_f32_16x16x32_f16(hf[i], bfx[3][i], a3, 0, 0, 0);
      }
    }

    // C/D layout: col = lane&15, row = q4*4 + reg. Stage partials (parity buf).
    const int par = t & 1;
#pragma unroll
    for (int r = 0; r < 4; ++r) {
      red[par][wave][q4 * 4 + r][     u16v] = a0[r];
      red[par][wave][q4 * 4 + r][16 + u16v] = a1[r];
      red[par][wave][q4 * 4 + r][32 + u16v] = a2[r];
      red[par][wave][q4 * 4 + r][48 + u16v] = a3[r];
    }
    __syncthreads();   // the ONLY barrier per step (parity buffer removes WAR)

    // Reduce 4 K-partials + bias, then LSTM cell math in fp32.
    float gi = bi, gf = bfg, gg = bg, go = bo;
#pragma unroll
    for (int w2 = 0; w2 < 4; ++w2) {
      gi += red[par][w2][er][     eu];
      gf += red[par][w2][er][16 + eu];
      gg += red[par][w2][er][32 + eu];
      go += red[par][w2][er][48 + eu];
    }
    c = fast_sigmoid(gf) * c + fast_sigmoid(gi) * fast_tanh(gg);
    float h = fast_sigmoid(go) * fast_tanh(c);

    // Publish h[t+1]: pack 4 lanes' halfwords into one 8B ATOMIC SWAP
    // (executes at the LLC; fire-and-forget). The data IS the flag:
    // consumers detect non-sentinel halfwords at 8B granularity.
    {
      unsigned int v = f2h_bits(h);
      unsigned int partner = (unsigned int)__shfl_xor((int)v, 1);
      unsigned int pair = (v & 0xFFFFu) | (partner << 16);      // even lanes
      unsigned int pair2 = (unsigned int)__shfl_xor((int)pair, 2);
      unsigned long long p8 = ((unsigned long long)pair2 << 32) | pair; // lane%4==0
      if ((tid & 3) == 0)
        (void)__hip_atomic_exchange(
            (unsigned long long*)(H16 + (size_t)(t + 1) * BH + puboff),
            p8, __ATOMIC_RELAXED, __HIP_MEMORY_SCOPE_AGENT);
    }
    if (t >= SEQ) out[(size_t)(t - SEQ) * BH + rge * 1024 + ub + eu] = h;
  }
#undef ISSUE_POLL
#undef CLEAN_CHECK
}

extern "C" void kernel_launch(void* const* d_in, const int* in_sizes, int n_in,
                              void* d_out, int out_size, void* d_ws, size_t ws_size,
                              hipStream_t stream) {
  const float* x    = (const float*)d_in[0];
  const float* hx0  = (const float*)d_in[1];
  const float* cx0  = (const float*)d_in[2];
  const float* W_ih = (const float*)d_in[3];
  const float* W_hh = (const float*)d_in[4];
  const float* b_ih = (const float*)d_in[5];
  const float* b_hh = (const float*)d_in[6];

  // Workspace: X16 (67.1 MB) | H16 (67.5 MB)  ~= 135 MB
  unsigned short* X16 = (unsigned short*)d_ws;
  unsigned short* H16 = X16 + (size_t)SEQ * BH;

  // Sentinel-fill H16 (0xFFFF halfwords), then cvt overwrites H[0] with hx0.
  hipMemsetAsync(H16, 0xFF, (size_t)NBUF * BH * sizeof(unsigned short), stream);
  cvt_kernel<<<1024, 256, 0, stream>>>(x, hx0, X16, H16);
  lstm_kernel<<<256, 256, 0, stream>>>(cx0, W_ih, W_hh, b_ih, b_hh,
                                       X16, H16, (float*)d_out);
}

// Round 9
// 1960.951 us; speedup vs baseline: 1.0687x; 1.0320x over previous
//
#include <hip/hip_runtime.h>

#define SEQ 512
#define TOT 514                 // 512 scan steps + 2 autoregressive steps
#define BH  65536               // 64 rows * 1024 hidden = elems per h/x timestep
#define NBUF (TOT + 1)          // h buffers: h[0]=hx0, h[t+1] = output of step t

typedef _Float16 f16x8 __attribute__((ext_vector_type(8)));
typedef float f32x4 __attribute__((ext_vector_type(4)));

__device__ __forceinline__ unsigned short f2h_bits(float f) {
  union { _Float16 h; unsigned short s; } u; u.h = (_Float16)f; return u.s;
}

__device__ __forceinline__ float fast_sigmoid(float x) {
  return 1.f / (1.f + __expf(-x));
}
__device__ __forceinline__ float fast_tanh(float x) {
  float e = __expf(-2.f * fabsf(x));
  float r = (1.f - e) / (1.f + e);
  return copysignf(r, x);
}

// SWAR: nonzero iff any 16-bit halfword of u equals 0xFFFF (the sentinel).
// |h|<1 strictly, so published f16 values can never be 0xFFFF (-NaN).
__device__ __forceinline__ unsigned long long dirty16(unsigned long long u) {
  unsigned long long n = ~u;   // sentinel halfword -> 0x0000
  return (n - 0x0001000100010001ULL) & ~n & 0x8000800080008000ULL;
}

// Convert x [512,64,1024] fp32 -> f16 (row-major) and hx0 -> blocked H layout
// H[t][q][s][r:16][u:16] (each producer block's slice = 512B contiguous).
__global__ void cvt_kernel(const float* __restrict__ x, const float* __restrict__ hx0,
                           unsigned short* __restrict__ X16, unsigned short* __restrict__ H0) {
  const long long n4x = (long long)SEQ * BH / 4;
  const long long n4h = BH / 4;
  const long long stride = (long long)gridDim.x * blockDim.x;
  for (long long i = (long long)blockIdx.x * blockDim.x + threadIdx.x;
       i < n4x + n4h; i += stride) {
    const float* src; unsigned short* dst;
    if (i < n4x) {
      src = x + 4 * i; dst = X16 + 4 * i;
    } else {
      long long e = (i - n4x) * 4;         // blocked linear offset
      int u0 = e & 15, r = (e >> 4) & 15, sl = (e >> 8) & 63, qq = (int)(e >> 14);
      src = hx0 + (qq * 16 + r) * 1024 + sl * 16 + u0;
      dst = H0 + e;
    }
    float4 v = *(const float4*)src;
    union { unsigned short s[4]; unsigned long long u; } pk;
    pk.s[0] = f2h_bits(v.x); pk.s[1] = f2h_bits(v.y);
    pk.s[2] = f2h_bits(v.z); pk.s[3] = f2h_bits(v.w);
    *(unsigned long long*)dst = pk.u;
  }
}

// Persistent LSTM kernel. Grid = 256 blocks (1/CU), now 512 threads = 8 WAVES
// (2 waves/SIMD). block -> (batch quarter q, unit slice ub = s*16).
// Wave w owns K-slice [w*128,+128) of BOTH W_ih and W_hh, register-resident.
// Sync design (r2/r6 structure, best measured 1737us; r7/r8 poll exotica
// reverted): H16 pre-filled 0xFF; publish = 8B atomic-swap; consumers poll
// the data words until no 0xFFFF halfword remains (batched selective sweep).
//
// Round-9 change: 2 WAVES/SIMD. Occupancy was 1 wave/SIMD; MfmaUtil 13% at
// 64 MFMAs/wave => ~16.5 cyc/MFMA = dependent-chain-latency rate (4.85cyc
// throughput at peak). Two co-resident waves interleave in the MFMA pipe
// (M-segment ~1050 -> ~450 cyc) and overlap each other's poll waits.
// K split 8-way: B-frags halve (-128 VGPR, enabling the occupancy), poll
// chunks halve (4/wave); costs an 8-way reduce (+~100cyc) and a half-idle
// cell phase (off critical path). Producer-union gating is UNCHANGED.
__global__ __launch_bounds__(512, 2)
void lstm_kernel(const float* __restrict__ cx0,
                 const float* __restrict__ W_ih, const float* __restrict__ W_hh,
                 const float* __restrict__ b_ih, const float* __restrict__ b_hh,
                 const unsigned short* __restrict__ X16,
                 unsigned short* __restrict__ H16,
                 float* __restrict__ out) {
  __shared__ float red[2][8][16][80];       // [parity][wave][m][n]  (80KB)

  const int tid  = threadIdx.x;
  const int wave = tid >> 6;                // 0..7
  const int lane = tid & 63;
  const int u16v = lane & 15;               // MFMA m (A row) / n (B col) index
  const int q4   = lane >> 4;               // MFMA quad
  // XCD-clustered mapping: blocks round-robin XCDs by blockIdx.x & 7, so
  // quarter q = pair of XCDs {2q, 2q+1}; s bijective within the quarter.
  const int q    = (blockIdx.x & 7) >> 1;                       // batch quarter
  const int s    = (blockIdx.x >> 3) | ((blockIdx.x & 1) << 5); // unit-slice
  const int ub   = s * 16;                  // hidden-unit base
  const int kb   = wave * 128;              // this wave's K-slice (both matrices)

  // ---------- stage weight B-fragments into registers (fp32 -> f16) ----------
  // B layout for mfma_f32_16x16x32_f16: B[k = q4*8+j][n = lane&15]; row-major
  // W[col][k] matches k-contiguity exactly. 4 k-iters of 32 per wave.
  f16x8 bfx[4][4], bfh[4][4];
#pragma unroll
  for (int g = 0; g < 4; ++g) {
    const float* wi = W_ih + (size_t)((g << 10) + ub + u16v) * 1024 + kb + q4 * 8;
    const float* wh = W_hh + (size_t)((g << 10) + ub + u16v) * 1024 + kb + q4 * 8;
#pragma unroll
    for (int i = 0; i < 4; ++i) {
      float4 x0 = *(const float4*)(wi + i * 32);
      float4 x1 = *(const float4*)(wi + i * 32 + 4);
      float4 h0 = *(const float4*)(wh + i * 32);
      float4 h1 = *(const float4*)(wh + i * 32 + 4);
      f16x8 bx, bh;
      bx[0] = (_Float16)x0.x; bx[1] = (_Float16)x0.y; bx[2] = (_Float16)x0.z; bx[3] = (_Float16)x0.w;
      bx[4] = (_Float16)x1.x; bx[5] = (_Float16)x1.y; bx[6] = (_Float16)x1.z; bx[7] = (_Float16)x1.w;
      bh[0] = (_Float16)h0.x; bh[1] = (_Float16)h0.y; bh[2] = (_Float16)h0.z; bh[3] = (_Float16)h0.w;
      bh[4] = (_Float16)h1.x; bh[5] = (_Float16)h1.y; bh[6] = (_Float16)h1.z; bh[7] = (_Float16)h1.w;
      bfx[g][i] = bx; bfh[g][i] = bh;
    }
  }

  // ---------- per-thread recurrent state (threads 0..255 only) ----------
  const int er = tid >> 4, eu = tid & 15;   // (row-in-quarter, unit-in-slice)
  const int rge = q * 16 + er;              // global batch row
  const bool cellth = (tid < 256);
  float c = 0.f, bi = 0.f, bfg = 0.f, bg = 0.f, bo = 0.f;
  if (cellth) {
    c   = cx0[rge * 1024 + ub + eu];
    bi  = b_ih[       ub + eu] + b_hh[       ub + eu];
    bfg = b_ih[1024 + ub + eu] + b_hh[1024 + ub + eu];
    bg  = b_ih[2048 + ub + eu] + b_hh[2048 + ub + eu];
    bo  = b_ih[3072 + ub + eu] + b_hh[3072 + ub + eu];
  }

  // x A-fragment base (row-major [64,1024] f16): A[m=lane&15][k=q4*8+j]
  const size_t xbase = (size_t)(q * 16 + u16v) * 1024 + kb + q4 * 8;
  // h A-fragment base (blocked layout): element offset within a timestep.
  // Wave K-slice 128 units = 8 slices; chunk i covers slices [8w+2i, +2).
  const size_t hfrag = ((size_t)(q * 64 + wave * 8 + (q4 >> 1)) << 8)
                       + u16v * 16 + (q4 & 1) * 8;     // + i*512 per k-iter
  // this block's publish offset within a timestep (contiguous per block)
  const size_t puboff = ((size_t)(q * 64 + s) << 8) + tid;

  for (int t = 0; t < TOT; ++t) {
    f32x4 a0 = {0.f, 0.f, 0.f, 0.f}, a1 = a0, a2 = a0, a3 = a0;
    const bool xphase = (t < SEQ);

    // ===== load x A-fragments first (oldest in vmcnt queue) =====
    f16x8 xf[4];
    if (xphase) {
      const unsigned short* xs = X16 + (size_t)t * BH + xbase;
#pragma unroll
      for (int i = 0; i < 4; ++i) xf[i] = *(const f16x8*)(xs + i * 32);
    }

    // ===== issue FIRST h-poll attempt before the x-MFMAs =====
    const unsigned short* hs = H16 + (size_t)t * BH + hfrag;
    union { unsigned long long u[2]; f16x8 v; } cv[4];
#pragma unroll
    for (int i = 0; i < 4; ++i) {
      const unsigned short* p = hs + i * 512;
      cv[i].u[0] = __hip_atomic_load((const unsigned long long*)p,
                                     __ATOMIC_RELAXED, __HIP_MEMORY_SCOPE_AGENT);
      cv[i].u[1] = __hip_atomic_load((const unsigned long long*)(p + 4),
                                     __ATOMIC_RELAXED, __HIP_MEMORY_SCOPE_AGENT);
    }
    __builtin_amdgcn_sched_barrier(0);   // keep cv issue ahead of the MFMAs

    // ===== x-phase: no dependency on h[t]; overlaps first poll transit =====
    if (xphase) {
#pragma unroll
      for (int i = 0; i < 4; ++i) {
        a0 = __builtin_amdgcn_mfma_f32_16x16x32_f16(xf[i], bfx[0][i], a0, 0, 0, 0);
        a1 = __builtin_amdgcn_mfma_f32_16x16x32_f16(xf[i], bfx[1][i], a1, 0, 0, 0);
        a2 = __builtin_amdgcn_mfma_f32_16x16x32_f16(xf[i], bfx[2][i], a2, 0, 0, 0);
        a3 = __builtin_amdgcn_mfma_f32_16x16x32_f16(xf[i], bfx[3][i], a3, 0, 0, 0);
      }
    }

    // ===== poll: batched selective re-poll (r2 structure) =====
    unsigned long long d[4];
#pragma unroll
    for (int i = 0; i < 4; ++i)
      d[i] = dirty16(cv[i].u[0]) | dirty16(cv[i].u[1]);
    while (true) {
      unsigned long long agg = 0;
#pragma unroll
      for (int i = 0; i < 4; ++i) agg |= d[i];
      if (__all(agg == 0)) break;

      unsigned long long nv0[4], nv1[4];
      int rl[4];
#pragma unroll
      for (int i = 0; i < 4; ++i) {
        rl[i] = __any(d[i] != 0);          // wave-uniform reload decision
        if (rl[i]) {
          const unsigned short* p = hs + i * 512;
          nv0[i] = __hip_atomic_load((const unsigned long long*)p,
                                     __ATOMIC_RELAXED, __HIP_MEMORY_SCOPE_AGENT);
          nv1[i] = __hip_atomic_load((const unsigned long long*)(p + 4),
                                     __ATOMIC_RELAXED, __HIP_MEMORY_SCOPE_AGENT);
        }
      }
      __builtin_amdgcn_sched_barrier(0);   // pin: all issues before any use
#pragma unroll
      for (int i = 0; i < 4; ++i) {
        if (rl[i]) {
          cv[i].u[0] = nv0[i]; cv[i].u[1] = nv1[i];
          d[i] = dirty16(nv0[i]) | dirty16(nv1[i]);
        }
      }
    }

    f16x8 hf[4];
#pragma unroll
    for (int i = 0; i < 4; ++i) hf[i] = cv[i].v;
#pragma unroll
    for (int i = 0; i < 4; ++i) {
      a0 = __builtin_amdgcn_mfma_f32_16x16x32_f16(hf[i], bfh[0][i], a0, 0, 0, 0);
      a1 = __builtin_amdgcn_mfma_f32_16x16x32_f16(hf[i], bfh[1][i], a1, 0, 0, 0);
      a2 = __builtin_amdgcn_mfma_f32_16x16x32_f16(hf[i], bfh[2][i], a2, 0, 0, 0);
      a3 = __builtin_amdgcn_mfma_f32_16x16x32_f16(hf[i], bfh[3][i], a3, 0, 0, 0);
    }
    if (t >= SEQ) {  // autoregressive: x_t := h[t], add the W_ih side too
#pragma unroll
      for (int i = 0; i < 4; ++i) {
        a0 = __builtin_amdgcn_mfma_f32_16x16x32_f16(hf[i], bfx[0][i], a0, 0, 0, 0);
        a1 = __builtin_amdgcn_mfma_f32_16x16x32_f16(hf[i], bfx[1][i], a1, 0, 0, 0);
        a2 = __builtin_amdgcn_mfma_f32_16x16x32_f16(hf[i], bfx[2][i], a2, 0, 0, 0);
        a3 = __builtin_amdgcn_mfma_f32_16x16x32_f16(hf[i], bfx[3][i], a3, 0, 0, 0);
      }
    }

    // C/D layout: col = lane&15, row = q4*4 + reg. Stage partials (parity buf).
    const int par = t & 1;
#pragma unroll
    for (int r = 0; r < 4; ++r) {
      red[par][wave][q4 * 4 + r][     u16v] = a0[r];
      red[par][wave][q4 * 4 + r][16 + u16v] = a1[r];
      red[par][wave][q4 * 4 + r][32 + u16v] = a2[r];
      red[par][wave][q4 * 4 + r][48 + u16v] = a3[r];
    }
    __syncthreads();   // the ONLY barrier per step (parity buffer removes WAR)

    // Reduce 8 K-partials + bias, then LSTM cell math (threads 0..255).
    if (cellth) {
      float gi = bi, gf = bfg, gg = bg, go = bo;
#pragma unroll
      for (int w2 = 0; w2 < 8; ++w2) {
        gi += red[par][w2][er][     eu];
        gf += red[par][w2][er][16 + eu];
        gg += red[par][w2][er][32 + eu];
        go += red[par][w2][er][48 + eu];
      }
      c = fast_sigmoid(gf) * c + fast_sigmoid(gi) * fast_tanh(gg);
      float h = fast_sigmoid(go) * fast_tanh(c);

      // Publish h[t+1]: pack 4 lanes' halfwords into one 8B ATOMIC SWAP
      // (executes at the LLC; fire-and-forget). The data IS the flag.
      unsigned int v = f2h_bits(h);
      unsigned int partner = (unsigned int)__shfl_xor((int)v, 1);
      unsigned int pair = (v & 0xFFFFu) | (partner << 16);      // even lanes
      unsigned int pair2 = (unsigned int)__shfl_xor((int)pair, 2);
      unsigned long long p8 = ((unsigned long long)pair2 << 32) | pair; // lane%4==0
      if ((tid & 3) == 0)
        (void)__hip_atomic_exchange(
            (unsigned long long*)(H16 + (size_t)(t + 1) * BH + puboff),
            p8, __ATOMIC_RELAXED, __HIP_MEMORY_SCOPE_AGENT);
      if (t >= SEQ) out[(size_t)(t - SEQ) * BH + rge * 1024 + ub + eu] = h;
    }
  }
}

extern "C" void kernel_launch(void* const* d_in, const int* in_sizes, int n_in,
                              void* d_out, int out_size, void* d_ws, size_t ws_size,
                              hipStream_t stream) {
  const float* x    = (const float*)d_in[0];
  const float* hx0  = (const float*)d_in[1];
  const float* cx0  = (const float*)d_in[2];
  const float* W_ih = (const float*)d_in[3];
  const float* W_hh = (const float*)d_in[4];
  const float* b_ih = (const float*)d_in[5];
  const float* b_hh = (const float*)d_in[6];

  // Workspace: X16 (67.1 MB) | H16 (67.5 MB)  ~= 135 MB
  unsigned short* X16 = (unsigned short*)d_ws;
  unsigned short* H16 = X16 + (size_t)SEQ * BH;

  // Sentinel-fill H16 (0xFFFF halfwords), then cvt overwrites H[0] with hx0.
  hipMemsetAsync(H16, 0xFF, (size_t)NBUF * BH * sizeof(unsigned short), stream);
  cvt_kernel<<<1024, 256, 0, stream>>>(x, hx0, X16, H16);
  lstm_kernel<<<256, 512, 0, stream>>>(cx0, W_ih, W_hh, b_ih, b_hh,
                                       X16, H16, (float*)d_out);
}

// Round 10
// 1774.918 us; speedup vs baseline: 1.1807x; 1.1048x over previous
//
#include <hip/hip_runtime.h>

#define SEQ 512
#define TOT 514                 // 512 scan steps + 2 autoregressive steps
#define BH  65536               // 64 rows * 1024 hidden = elems per h/x timestep
#define NBUF (TOT + 1)          // h buffers: h[0]=hx0, h[t+1] = output of step t

typedef _Float16 f16x8 __attribute__((ext_vector_type(8)));
typedef float f32x4 __attribute__((ext_vector_type(4)));

__device__ __forceinline__ unsigned short f2h_bits(float f) {
  union { _Float16 h; unsigned short s; } u; u.h = (_Float16)f; return u.s;
}

__device__ __forceinline__ float fast_sigmoid(float x) {
  return 1.f / (1.f + __expf(-x));
}
__device__ __forceinline__ float fast_tanh(float x) {
  float e = __expf(-2.f * fabsf(x));
  float r = (1.f - e) / (1.f + e);
  return copysignf(r, x);
}

// SWAR: nonzero iff any 16-bit halfword of u equals 0xFFFF (the sentinel).
// |h|<1 strictly, so published f16 values can never be 0xFFFF (-NaN).
__device__ __forceinline__ unsigned long long dirty16(unsigned long long u) {
  unsigned long long n = ~u;   // sentinel halfword -> 0x0000
  return (n - 0x0001000100010001ULL) & ~n & 0x8000800080008000ULL;
}

// Convert x [512,64,1024] fp32 -> f16 (row-major) and hx0 -> blocked H layout
// H[t][q][s][r:16][u:16] (each producer block's slice = 512B contiguous).
__global__ void cvt_kernel(const float* __restrict__ x, const float* __restrict__ hx0,
                           unsigned short* __restrict__ X16, unsigned short* __restrict__ H0) {
  const long long n4x = (long long)SEQ * BH / 4;
  const long long n4h = BH / 4;
  const long long stride = (long long)gridDim.x * blockDim.x;
  for (long long i = (long long)blockIdx.x * blockDim.x + threadIdx.x;
       i < n4x + n4h; i += stride) {
    const float* src; unsigned short* dst;
    if (i < n4x) {
      src = x + 4 * i; dst = X16 + 4 * i;
    } else {
      long long e = (i - n4x) * 4;         // blocked linear offset
      int u0 = e & 15, r = (e >> 4) & 15, sl = (e >> 8) & 63, qq = (int)(e >> 14);
      src = hx0 + (qq * 16 + r) * 1024 + sl * 16 + u0;
      dst = H0 + e;
    }
    float4 v = *(const float4*)src;
    union { unsigned short s[4]; unsigned long long u; } pk;
    pk.s[0] = f2h_bits(v.x); pk.s[1] = f2h_bits(v.y);
    pk.s[2] = f2h_bits(v.z); pk.s[3] = f2h_bits(v.w);
    *(unsigned long long*)dst = pk.u;
  }
}

// Persistent LSTM kernel. Grid = 256 blocks (1/CU), 256 threads (4 waves).
// block -> (batch quarter q: rows [16q,16q+16), unit slice ub = s*16).
// Wave w owns K-slice [w*256,+256) of BOTH W_ih and W_hh, register-resident.
// Sync design: NO flags. H16 pre-filled 0xFF; producers publish h via 2B
// relaxed agent stores; consumers poll the data words until no 0xFFFF
// halfword remains (batched selective sweep -- best-measured structure).
//
// Round-10: REVERT to the r6 champion structure (r7/r8/r9 sync experiments
// all regressed; step period is a rendezvous floor insensitive to poll/
// publish mechanics and occupancy). Tail-only micro-opts:
//  (1) gate-contiguous LDS staging: {a0,a1,a2,a3}[r] as one f32x4 ->
//      ds_write_b128 x4 (was b32 x16); reduce = ds_read_b128 x4 (was x16).
//  (2) immediate per-thread 2B publish (r0 protocol, measured == packed):
//      drops the 2-shfl pack chain off the critical path.
//  (3) LDS pad 68 (layout re-derived conflict-safe for b128 pattern).
__global__ __launch_bounds__(256, 1)
void lstm_kernel(const float* __restrict__ cx0,
                 const float* __restrict__ W_ih, const float* __restrict__ W_hh,
                 const float* __restrict__ b_ih, const float* __restrict__ b_hh,
                 const unsigned short* __restrict__ X16,
                 unsigned short* __restrict__ H16,
                 float* __restrict__ out) {
  // [parity][wave][m=16][4*n : gate-contiguous], pad 64->68 (272B rows, 16B-aligned)
  __shared__ float red[2][4][16][68];

  const int tid  = threadIdx.x;
  const int wave = tid >> 6;
  const int lane = tid & 63;
  const int u16v = lane & 15;               // MFMA m (A row) / n (B col) index
  const int q4   = lane >> 4;               // MFMA quad
  // XCD-clustered mapping: blocks round-robin XCDs by blockIdx.x & 7, so
  // quarter q = pair of XCDs {2q, 2q+1}; s bijective within the quarter.
  const int q    = (blockIdx.x & 7) >> 1;                       // batch quarter
  const int s    = (blockIdx.x >> 3) | ((blockIdx.x & 1) << 5); // unit-slice
  const int ub   = s * 16;                  // hidden-unit base
  const int kb   = wave * 256;              // this wave's K-slice (both matrices)

  // ---------- stage weight B-fragments into registers (fp32 -> f16) ----------
  // B layout for mfma_f32_16x16x32_f16: B[k = q4*8+j][n = lane&15]; row-major
  // W[col][k] matches k-contiguity exactly.
  f16x8 bfx[4][8], bfh[4][8];
#pragma unroll
  for (int g = 0; g < 4; ++g) {
    const float* wi = W_ih + (size_t)((g << 10) + ub + u16v) * 1024 + kb + q4 * 8;
    const float* wh = W_hh + (size_t)((g << 10) + ub + u16v) * 1024 + kb + q4 * 8;
#pragma unroll
    for (int i = 0; i < 8; ++i) {
      float4 x0 = *(const float4*)(wi + i * 32);
      float4 x1 = *(const float4*)(wi + i * 32 + 4);
      float4 h0 = *(const float4*)(wh + i * 32);
      float4 h1 = *(const float4*)(wh + i * 32 + 4);
      f16x8 bx, bh;
      bx[0] = (_Float16)x0.x; bx[1] = (_Float16)x0.y; bx[2] = (_Float16)x0.z; bx[3] = (_Float16)x0.w;
      bx[4] = (_Float16)x1.x; bx[5] = (_Float16)x1.y; bx[6] = (_Float16)x1.z; bx[7] = (_Float16)x1.w;
      bh[0] = (_Float16)h0.x; bh[1] = (_Float16)h0.y; bh[2] = (_Float16)h0.z; bh[3] = (_Float16)h0.w;
      bh[4] = (_Float16)h1.x; bh[5] = (_Float16)h1.y; bh[6] = (_Float16)h1.z; bh[7] = (_Float16)h1.w;
      bfx[g][i] = bx; bfh[g][i] = bh;
    }
  }

  // ---------- per-thread recurrent state (elementwise mapping) ----------
  const int er = tid >> 4, eu = tid & 15;   // (row-in-quarter, unit-in-slice)
  const int rge = q * 16 + er;              // global batch row
  float c = cx0[rge * 1024 + ub + eu];
  const float bi  = b_ih[       ub + eu] + b_hh[       ub + eu];
  const float bfg = b_ih[1024 + ub + eu] + b_hh[1024 + ub + eu];
  const float bg  = b_ih[2048 + ub + eu] + b_hh[2048 + ub + eu];
  const float bo  = b_ih[3072 + ub + eu] + b_hh[3072 + ub + eu];

  // x A-fragment base (row-major [64,1024] f16): A[m=lane&15][k=q4*8+j]
  const size_t xbase = (size_t)(q * 16 + u16v) * 1024 + kb + q4 * 8;
  // h A-fragment base (blocked layout): element offset within a timestep
  const size_t hfrag = ((size_t)(q * 64 + wave * 16 + (q4 >> 1)) << 8)
                       + u16v * 16 + (q4 & 1) * 8;     // + i*512 per k-iter
  // this block's publish offset within a timestep (contiguous per block)
  const size_t puboff = ((size_t)(q * 64 + s) << 8) + tid;

  for (int t = 0; t < TOT; ++t) {
    f32x4 a0 = {0.f, 0.f, 0.f, 0.f}, a1 = a0, a2 = a0, a3 = a0;
    const bool xphase = (t < SEQ);

    // ===== load x A-fragments first (oldest in vmcnt queue) =====
    f16x8 xf[8];
    if (xphase) {
      const unsigned short* xs = X16 + (size_t)t * BH + xbase;
#pragma unroll
      for (int i = 0; i < 8; ++i) xf[i] = *(const f16x8*)(xs + i * 32);
    }

    // ===== issue FIRST h-poll attempt before the x-MFMAs =====
    // x-MFMAs only need xf (older in queue), so the compiler can wait with
    // a partial vmcnt and the cv round-trip hides under the MFMA block.
    const unsigned short* hs = H16 + (size_t)t * BH + hfrag;
    union { unsigned long long u[2]; f16x8 v; } cv[8];
#pragma unroll
    for (int i = 0; i < 8; ++i) {
      const unsigned short* p = hs + i * 512;
      cv[i].u[0] = __hip_atomic_load((const unsigned long long*)p,
                                     __ATOMIC_RELAXED, __HIP_MEMORY_SCOPE_AGENT);
      cv[i].u[1] = __hip_atomic_load((const unsigned long long*)(p + 4),
                                     __ATOMIC_RELAXED, __HIP_MEMORY_SCOPE_AGENT);
    }
    __builtin_amdgcn_sched_barrier(0);   // keep cv issue ahead of the MFMAs

    // ===== x-phase: no dependency on h[t]; overlaps first poll transit =====
    if (xphase) {
#pragma unroll
      for (int i = 0; i < 8; ++i) {
        a0 = __builtin_amdgcn_mfma_f32_16x16x32_f16(xf[i], bfx[0][i], a0, 0, 0, 0);
        a1 = __builtin_amdgcn_mfma_f32_16x16x32_f16(xf[i], bfx[1][i], a1, 0, 0, 0);
        a2 = __builtin_amdgcn_mfma_f32_16x16x32_f16(xf[i], bfx[2][i], a2, 0, 0, 0);
        a3 = __builtin_amdgcn_mfma_f32_16x16x32_f16(xf[i], bfx[3][i], a3, 0, 0, 0);
      }
    }

    // ===== poll: batched selective re-poll (champion structure) =====
    unsigned long long d[8];
#pragma unroll
    for (int i = 0; i < 8; ++i)
      d[i] = dirty16(cv[i].u[0]) | dirty16(cv[i].u[1]);
    while (true) {
      unsigned long long agg = 0;
#pragma unroll
      for (int i = 0; i < 8; ++i) agg |= d[i];
      if (__all(agg == 0)) break;

      unsigned long long nv0[8], nv1[8];
      int rl[8];
#pragma unroll
      for (int i = 0; i < 8; ++i) {
        rl[i] = __any(d[i] != 0);          // wave-uniform reload decision
        if (rl[i]) {
          const unsigned short* p = hs + i * 512;
          nv0[i] = __hip_atomic_load((const unsigned long long*)p,
                                     __ATOMIC_RELAXED, __HIP_MEMORY_SCOPE_AGENT);
          nv1[i] = __hip_atomic_load((const unsigned long long*)(p + 4),
                                     __ATOMIC_RELAXED, __HIP_MEMORY_SCOPE_AGENT);
        }
      }
      __builtin_amdgcn_sched_barrier(0);   // pin: all issues before any use
#pragma unroll
      for (int i = 0; i < 8; ++i) {
        if (rl[i]) {
          cv[i].u[0] = nv0[i]; cv[i].u[1] = nv1[i];
          d[i] = dirty16(nv0[i]) | dirty16(nv1[i]);
        }
      }
    }

    f16x8 hf[8];
#pragma unroll
    for (int i = 0; i < 8; ++i) hf[i] = cv[i].v;
#pragma unroll
    for (int i = 0; i < 8; ++i) {
      a0 = __builtin_amdgcn_mfma_f32_16x16x32_f16(hf[i], bfh[0][i], a0, 0, 0, 0);
      a1 = __builtin_amdgcn_mfma_f32_16x16x32_f16(hf[i], bfh[1][i], a1, 0, 0, 0);
      a2 = __builtin_amdgcn_mfma_f32_16x16x32_f16(hf[i], bfh[2][i], a2, 0, 0, 0);
      a3 = __builtin_amdgcn_mfma_f32_16x16x32_f16(hf[i], bfh[3][i], a3, 0, 0, 0);
    }
    if (t >= SEQ) {  // autoregressive: x_t := h[t], add the W_ih side too
#pragma unroll
      for (int i = 0; i < 8; ++i) {
        a0 = __builtin_amdgcn_mfma_f32_16x16x32_f16(hf[i], bfx[0][i], a0, 0, 0, 0);
        a1 = __builtin_amdgcn_mfma_f32_16x16x32_f16(hf[i], bfx[1][i], a1, 0, 0, 0);
        a2 = __builtin_amdgcn_mfma_f32_16x16x32_f16(hf[i], bfx[2][i], a2, 0, 0, 0);
        a3 = __builtin_amdgcn_mfma_f32_16x16x32_f16(hf[i], bfx[3][i], a3, 0, 0, 0);
      }
    }

    // C/D layout: col = lane&15, row = q4*4 + reg. Stage gate-contiguous:
    // red[par][wave][row][4*col + gate] via one ds_write_b128 per r.
    const int par = t & 1;
#pragma unroll
    for (int r = 0; r < 4; ++r) {
      f32x4 g4 = {a0[r], a1[r], a2[r], a3[r]};
      *(f32x4*)&red[par][wave][q4 * 4 + r][4 * u16v] = g4;
    }
    __syncthreads();   // the ONLY barrier per step (parity buffer removes WAR)

    // Reduce 4 K-partials (one b128 read per wave) + bias, then cell math.
    float gi = bi, gf = bfg, gg = bg, go = bo;
#pragma unroll
    for (int w2 = 0; w2 < 4; ++w2) {
      f32x4 g4 = *(const f32x4*)&red[par][w2][er][4 * eu];
      gi += g4[0]; gf += g4[1]; gg += g4[2]; go += g4[3];
    }
    c = fast_sigmoid(gf) * c + fast_sigmoid(gi) * fast_tanh(gg);
    float h = fast_sigmoid(go) * fast_tanh(c);

    // Publish h[t+1]: immediate per-thread 2B agent store (r0 protocol,
    // measured == packed 8B == atomic swap). No pack chain before the first
    // store issues. The data IS the flag: consumers detect non-sentinel
    // halfwords; an 8B poll word becomes clean when its 4 stores land.
    __hip_atomic_store(H16 + (size_t)(t + 1) * BH + puboff, f2h_bits(h),
                       __ATOMIC_RELAXED, __HIP_MEMORY_SCOPE_AGENT);
    if (t >= SEQ) out[(size_t)(t - SEQ) * BH + rge * 1024 + ub + eu] = h;
  }
}

extern "C" void kernel_launch(void* const* d_in, const int* in_sizes, int n_in,
                              void* d_out, int out_size, void* d_ws, size_t ws_size,
                              hipStream_t stream) {
  const float* x    = (const float*)d_in[0];
  const float* hx0  = (const float*)d_in[1];
  const float* cx0  = (const float*)d_in[2];
  const float* W_ih = (const float*)d_in[3];
  const float* W_hh = (const float*)d_in[4];
  const float* b_ih = (const float*)d_in[5];
  const float* b_hh = (const float*)d_in[6];

  // Workspace: X16 (67.1 MB) | H16 (67.5 MB)  ~= 135 MB
  unsigned short* X16 = (unsigned short*)d_ws;
  unsigned short* H16 = X16 + (size_t)SEQ * BH;

  // Sentinel-fill H16 (0xFFFF halfwords), then cvt overwrites H[0] with hx0.
  hipMemsetAsync(H16, 0xFF, (size_t)NBUF * BH * sizeof(unsigned short), stream);
  cvt_kernel<<<1024, 256, 0, stream>>>(x, hx0, X16, H16);
  lstm_kernel<<<256, 256, 0, stream>>>(cx0, W_ih, W_hh, b_ih, b_hh,
                                       X16, H16, (float*)d_out);
}